// Round 1
// baseline (120.551 us; speedup 1.0000x reference)
//
#include <hip/hip_runtime.h>

// Problem: N=8192 rows, D=1024 (D_IN == D_OUT == 1024).
// Reference scales scores by 1/1024^5 = 2^-50 -> softmax is EXACTLY uniform in
// fp32 (exp of |x|<6e-13 rounds to 1.0f). So out[i,:] = mean_j(v[j,:]) for all i,
// and mean_j(x @ Wv) = (mean_j x) @ Wv. Q/K/Wq/Wk are dead.

#define NROWS 8192
#define DDIM  1024

// ws layout (floats): [0..1023] colsum(x), [1024..2047] outrow
__global__ void init_ws_k(float* __restrict__ ws) {
    int t = threadIdx.x;                       // 256 threads, 1 block
    for (int i = t; i < 2 * DDIM; i += 256) ws[i] = 0.0f;
}

// Column sums of x. 256 blocks x 256 threads; block b covers rows [b*32, b*32+32).
// Thread t reads float4 column-group t of each row (coalesced 16B/lane).
__global__ void colsum_k(const float4* __restrict__ x4, float* __restrict__ colsum) {
    int t = threadIdx.x;
    int b = blockIdx.x;
    const float4* p = x4 + (size_t)b * 32 * (DDIM / 4) + t;
    float4 acc = make_float4(0.f, 0.f, 0.f, 0.f);
#pragma unroll
    for (int i = 0; i < 32; ++i) {
        float4 v = p[(size_t)i * (DDIM / 4)];
        acc.x += v.x; acc.y += v.y; acc.z += v.z; acc.w += v.w;
    }
    atomicAdd(&colsum[4 * t + 0], acc.x);
    atomicAdd(&colsum[4 * t + 1], acc.y);
    atomicAdd(&colsum[4 * t + 2], acc.z);
    atomicAdd(&colsum[4 * t + 3], acc.w);
}

// outrow[d] = (1/8192) * sum_k colsum[k] * Wv[k][d].
// 256 blocks: kc = blockIdx>>2 (16 k-values each), dc = blockIdx&3 (256 d each).
__global__ void matvec_k(const float* __restrict__ Wv, const float* __restrict__ colsum,
                         float* __restrict__ outrow) {
    int t  = threadIdx.x;
    int kc = blockIdx.x >> 2;
    int dc = blockIdx.x & 3;
    int d  = dc * 256 + t;
    int k0 = kc * 16;
    float acc = 0.f;
#pragma unroll
    for (int k = 0; k < 16; ++k) {
        acc += colsum[k0 + k] * Wv[(size_t)(k0 + k) * DDIM + d];
    }
    atomicAdd(&outrow[d], acc * (1.0f / (float)NROWS));
}

// Broadcast outrow into all 8192 rows of out. 512 blocks x 256 threads;
// thread t holds float4 col-group t, block b writes rows [b*16, b*16+16).
__global__ void bcast_k(const float4* __restrict__ outrow4, float4* __restrict__ out4) {
    int t = threadIdx.x;
    int b = blockIdx.x;
    float4 v = outrow4[t];
    float4* p = out4 + (size_t)b * 16 * (DDIM / 4) + t;
#pragma unroll
    for (int r = 0; r < 16; ++r) {
        p[(size_t)r * (DDIM / 4)] = v;
    }
}

extern "C" void kernel_launch(void* const* d_in, const int* in_sizes, int n_in,
                              void* d_out, int out_size, void* d_ws, size_t ws_size,
                              hipStream_t stream) {
    const float* x  = (const float*)d_in[0];
    // d_in[1] = Wq, d_in[2] = Wk are provably unused (softmax is exactly uniform).
    const float* Wv = (const float*)d_in[3];
    float* ws     = (float*)d_ws;
    float* colsum = ws;            // 1024 floats
    float* outrow = ws + DDIM;     // 1024 floats
    float* out    = (float*)d_out; // 8192 x 1024 fp32

    hipLaunchKernelGGL(init_ws_k, dim3(1),   dim3(256), 0, stream, ws);
    hipLaunchKernelGGL(colsum_k,  dim3(256), dim3(256), 0, stream, (const float4*)x, colsum);
    hipLaunchKernelGGL(matvec_k,  dim3(256), dim3(256), 0, stream, Wv, colsum, outrow);
    hipLaunchKernelGGL(bcast_k,   dim3(512), dim3(256), 0, stream, (const float4*)outrow, (float4*)out);
}